// Round 1
// baseline (2257.540 us; speedup 1.0000x reference)
//
#include <hip/hip_runtime.h>
#include <hip/hip_bf16.h>

#define NSEQ 512
#define SEGS 511     // L-1
#define CIN  32
#define CHID 64
#define CHH  128

__device__ __forceinline__ float rl(float v, int lane) {
    return __int_as_float(__builtin_amdgcn_readlane(__float_as_int(v), lane));
}

__device__ __forceinline__ float tanhf_fast(float x) {
    // tanh(x) = sign(x) * (1 - e) / (1 + e),  e = exp(-2|x|)  — no overflow path
    float ax = fabsf(x);
    float e = __expf(-2.0f * ax);
#if __has_builtin(__builtin_amdgcn_rcpf)
    float r = (1.0f - e) * __builtin_amdgcn_rcpf(1.0f + e);
#else
    float r = (1.0f - e) / (1.0f + e);
#endif
    return copysignf(r, x);
}

// One sequence per block. 2 waves: wave A owns u-rows 0..47 (z part),
// wave B owns u-rows 48..95 (z tail + all 32 spline channels).
// lane m of each wave holds z_m; h split as (h_lane, h_{lane+64}).
__global__ __launch_bounds__(128, 1) void node_kernel(
    const float* __restrict__ cA, const float* __restrict__ cB,
    const float* __restrict__ cC, const float* __restrict__ cD,
    const int*   __restrict__ final_index,
    const float* __restrict__ W_init, const float* __restrict__ b_init,
    const float* __restrict__ W1, const float* __restrict__ b1,
    const float* __restrict__ W2, const float* __restrict__ b2,
    const float* __restrict__ W_out, const float* __restrict__ b_out,
    float* __restrict__ out)
{
    __shared__ float hpart[2][CHH];
    __shared__ float zpart[2][CHID];

    const int b    = blockIdx.x;
    const int lane = threadIdx.x & 63;
    const int wid  = threadIdx.x >> 6;
    const bool isB = (wid == 1);

    const float* a_ptr = cA + (size_t)b * SEGS * CIN;
    const float* bp    = cB + (size_t)b * SEGS * CIN;
    const float* cp    = cC + (size_t)b * SEGS * CIN;
    const float* dp    = cD + (size_t)b * SEGS * CIN;
    const int ch = lane & 31;

    // ---- weights into registers (per-lane columns) ----
    float w1lo[48], w1hi[48], w2c[64];
    const int rbase = isB ? 48 : 0;
#pragma unroll
    for (int i = 0; i < 48; ++i) {
        w1lo[i] = W1[(rbase + i) * CHH + lane];
        w1hi[i] = W1[(rbase + i) * CHH + 64 + lane];
    }
    const int jbase = isB ? 64 : 0;
#pragma unroll
    for (int j = 0; j < 64; ++j) w2c[j] = W2[(jbase + j) * CHID + lane];

    const float b1lo = b1[lane], b1hi = b1[64 + lane], b2m = b2[lane];

    // ---- z0 = X(0) @ W_init + b_init ;  X(0) = a[:,0] ----
    float z = b_init[lane];
    {
        float a0 = a_ptr[ch];
#pragma unroll
        for (int i = 0; i < 32; ++i)
            z = fmaf(rl(a0, i), W_init[i * CHID + lane], z);
    }

    const int fi = final_index[b];

    // current-step spline coeffs (segment 0), wave B only
    float acur = 0.f, bcc = 0.f, ccc = 0.f, dcc = 0.f;
    if (isB) {
        acur = a_ptr[ch];
        bcc  = bp[ch];
        ccc  = cp[ch];
        dcc  = dp[ch];
    }

    float k1 = 0.f, k2 = 0.f, k3 = 0.f;

    for (int t = 0; t < fi; ++t) {
        float an_l = 0.f, bn = 0.f, cn = 0.f, dn = 0.f;
        float x13 = 0.f, x23 = 0.f, xb = 0.f;
        if (isB) {
            // prefetch next segment's coeffs (clamped); an_l is also X(t+1) for k4
            const int tn  = (t + 1 < SEGS) ? (t + 1) : (SEGS - 1);
            const int off = tn * CIN + ch;
            an_l = a_ptr[off];
            bn   = bp[off];
            cn   = cp[off];
            dn   = dp[off];
            // reference spline: inner = 0.5*two_c + three_d*(frac/3); inner = b + inner*frac; X = a + inner*frac
            float i13 = fmaf(dcc, 1.0f / 9.0f, 0.5f * ccc);
            x13 = fmaf(fmaf(i13, 1.0f / 3.0f, bcc), 1.0f / 3.0f, acur);
            float i23 = fmaf(dcc, 2.0f / 9.0f, 0.5f * ccc);
            x23 = fmaf(fmaf(i23, 2.0f / 3.0f, bcc), 2.0f / 3.0f, acur);
            // X(t+1): segment t+1 at frac 0 (== a[t+1]) except last step: frac 1 on segment 510
            xb = (t < SEGS - 1) ? an_l
                                : (acur + (bcc + (0.5f * ccc + dcc * (1.0f / 3.0f))));
        }

        float k4 = 0.f;
#pragma unroll
        for (int s = 0; s < 4; ++s) {
            // RK4 3/8-rule stage inputs (dt = 1)
            float ys = z;
            if (s == 1)      ys = fmaf(k1, 1.0f / 3.0f, z);
            else if (s == 2) ys = z + (k2 - k1 * (1.0f / 3.0f));
            else if (s == 3) ys = z + (k1 - k2 + k3);
            float xc = (s == 0) ? acur : (s == 1) ? x13 : (s == 2) ? x23 : xb;

            // ---- matmul1 partial: h_j += sum_i u_i * W1[i][j] over this wave's i-range ----
            float hA = 0.f, hB = 0.f;
            if (!isB) {
#pragma unroll
                for (int i = 0; i < 48; ++i) {
                    float u = rl(ys, i);
                    hA = fmaf(u, w1lo[i], hA);
                    hB = fmaf(u, w1hi[i], hB);
                }
            } else {
#pragma unroll
                for (int i = 0; i < 16; ++i) {
                    float u = rl(ys, 48 + i);
                    hA = fmaf(u, w1lo[i], hA);
                    hB = fmaf(u, w1hi[i], hB);
                }
#pragma unroll
                for (int i = 0; i < 32; ++i) {
                    float u = rl(xc, i);
                    hA = fmaf(u, w1lo[16 + i], hA);
                    hB = fmaf(u, w1hi[16 + i], hB);
                }
            }
            hpart[wid][lane]      = hA;
            hpart[wid][64 + lane] = hB;
            __syncthreads();
            float h0 = tanhf_fast(hpart[0][lane] + hpart[1][lane] + b1lo);
            float h1 = tanhf_fast(hpart[0][64 + lane] + hpart[1][64 + lane] + b1hi);

            // ---- matmul2 partial: K-split (wave A: j=0..63 via h0, wave B: j=64..127 via h1) ----
            float hsel = isB ? h1 : h0;
            float za = 0.f;
#pragma unroll
            for (int j = 0; j < 64; ++j)
                za = fmaf(rl(hsel, j), w2c[j], za);
            zpart[wid][lane] = za;
            __syncthreads();
            float k = tanhf_fast(zpart[0][lane] + zpart[1][lane] + b2m);
            if (s == 0)      k1 = k;
            else if (s == 1) k2 = k;
            else if (s == 2) k3 = k;
            else             k4 = k;
        }
        z += (k1 + 3.0f * (k2 + k3) + k4) * 0.125f;
        if (isB) { acur = an_l; bcc = bn; ccc = cn; dcc = dn; }
    }

    // ---- out[b] = z_fi @ W_out + b_out ----
    if (wid == 0 && lane < 10) {
        float acc = b_out[lane];
#pragma unroll
        for (int m = 0; m < 64; ++m)
            acc = fmaf(rl(z, m), W_out[m * 10 + lane], acc);
        out[b * 10 + lane] = acc;
    }
}

extern "C" void kernel_launch(void* const* d_in, const int* in_sizes, int n_in,
                              void* d_out, int out_size, void* d_ws, size_t ws_size,
                              hipStream_t stream) {
    const float* cA     = (const float*)d_in[1];
    const float* cBc    = (const float*)d_in[2];
    const float* cCc    = (const float*)d_in[3];
    const float* cDc    = (const float*)d_in[4];
    const int*   fidx   = (const int*)d_in[5];
    const float* W_init = (const float*)d_in[6];
    const float* b_init = (const float*)d_in[7];
    const float* W1     = (const float*)d_in[8];
    const float* b1     = (const float*)d_in[9];
    const float* W2     = (const float*)d_in[10];
    const float* b2     = (const float*)d_in[11];
    const float* W_out  = (const float*)d_in[12];
    const float* b_out  = (const float*)d_in[13];

    node_kernel<<<dim3(NSEQ), dim3(128), 0, stream>>>(
        cA, cBc, cCc, cDc, fidx, W_init, b_init, W1, b1, W2, b2, W_out, b_out,
        (float*)d_out);
}